// Round 5
// baseline (1520.736 us; speedup 1.0000x reference)
//
#include <hip/hip_runtime.h>
#include <math.h>

typedef unsigned short u16;
typedef short s16x8 __attribute__((ext_vector_type(8)));
typedef float f32x4 __attribute__((ext_vector_type(4)));

#define NITER 32   // K=1024 / BK=32
#define ARW 72     // u16 per A LDS row: [32 hi][32 lo][8 pad] = 144 B

// Pre-split, transposed weights: layout [kb 32][gate 5][j 512][k 32]
__device__ __align__(16) u16 g_Bhi[1024 * 2560];
__device__ __align__(16) u16 g_Blo[1024 * 2560];

__device__ __forceinline__ u16 f2bf(float x) {
    unsigned u = __float_as_uint(x);
    u += 0x7fffu + ((u >> 16) & 1u);       // RNE
    return (u16)(u >> 16);
}
__device__ __forceinline__ float bf2f(u16 h) { return __uint_as_float(((unsigned)h) << 16); }
__device__ __forceinline__ float sigm(float x) { return 1.0f / (1.0f + expf(-x)); }
__device__ __forceinline__ unsigned pk(u16 a, u16 b) { return (unsigned)a | ((unsigned)b << 16); }

// ---------------- weight split+transpose: W[k][col] f32 -> [kb][g][j][k] bf16 hi/lo ----------
__global__ __launch_bounds__(256)
void wsplit_kernel(const float* __restrict__ Wiou, const float* __restrict__ Wf)
{
    __shared__ float tile[32][65];
    const int kb = blockIdx.x;           // 0..31
    const int cb = blockIdx.y;           // 0..39
    const int t  = threadIdx.x;
    const int c0 = cb * 64;

    {   // load 32k x 64c, coalesced on cols
        const int kk  = t >> 3;          // 0..31
        const int cu0 = (t & 7) * 8;     // 0..56
        const int k   = kb * 32 + kk;
#pragma unroll
        for (int u = 0; u < 8; u++) {
            int c = c0 + cu0 + u;
            float v = (c < 1536) ? Wiou[(size_t)k * 1536 + c]
                                 : Wf[(size_t)k * 1024 + (c - 1536)];
            tile[kk][cu0 + u] = v;
        }
    }
    __syncthreads();
    {   // write transposed, split, coalesced on dest
        const int jl = t >> 2;           // 0..63
        const int kc = (t & 3) * 8;      // 0,8,16,24
        const int g  = c0 >> 9;
        const int j  = (c0 & 511) + jl;
        size_t dst = (((size_t)kb * 5 + g) * 512 + j) * 32 + kc;
        unsigned ph[4], pl[4];
#pragma unroll
        for (int u = 0; u < 4; u++) {
            float v0 = tile[kc + 2 * u][jl];
            float v1 = tile[kc + 2 * u + 1][jl];
            u16 h0 = f2bf(v0), h1 = f2bf(v1);
            u16 l0 = f2bf(v0 - bf2f(h0)), l1 = f2bf(v1 - bf2f(h1));
            ph[u] = pk(h0, h1);
            pl[u] = pk(l0, l1);
        }
        *(uint4*)(g_Bhi + dst) = make_uint4(ph[0], ph[1], ph[2], ph[3]);
        *(uint4*)(g_Blo + dst) = make_uint4(pl[0], pl[1], pl[2], pl[3]);
    }
}

// ---------------- one tree level: split-bf16 MFMA GEMM + fused LSTM epilogue ----------------
// H global layout: per row: 1024 u16 = 32 chunks x {16 hi, 16 lo}. A-row = left||right contiguous.
// A: LDS-staged (shared by 4 wc-waves), combined 144B rows, double-buffered (37 KB total).
// B: global -> REGISTERS (per-wave coalesced 1KB fragment loads, L2-resident after jg pinning),
//    double-buffered static reg sets (even/odd unrolled x2).
template<bool LEAF>
__global__ __launch_bounds__(512, 2)
void level_mfma(const u16* __restrict__ Hc, const float* __restrict__ Cc,
                const int* __restrict__ tokens, const float* __restrict__ emb,
                const float* __restrict__ b_iou, const float* __restrict__ b_f,
                u16* __restrict__ Hp, float* __restrict__ Cp,
                int np, int lgnp)
{
    __shared__ __align__(16) u16 Ac[2][128 * ARW];   // 2 x 18.4 KB

    const int tid = threadIdx.x;
    const int jg  = blockIdx.x;          // 0..7 -> XCD pinning via %8
    const int m0  = blockIdx.y * 128;
    const int j0  = jg * 64;
    const int nc  = np * 2;
    const int M   = np * 64;

    // wave compute roles: 8 waves = 2 (row halves) x 4 (col groups)
    const int w    = tid >> 6;
    const int lane = tid & 63;
    const int il   = lane & 15;
    const int kq   = lane >> 4;
    const int wm   = w & 1;              // rows wm*64 .. +63
    const int wc   = w >> 1;             // j sub-range wc*16 .. +15

    f32x4 acc[4][5];                     // [rowfrag][gate]
#pragma unroll
    for (int rf = 0; rf < 4; rf++)
#pragma unroll
        for (int g = 0; g < 5; g++) acc[rf][g] = (f32x4)0.0f;

    // ---- A staging role: row rA (0..127), quarter qA (0..3) ----
    const int rA = tid >> 2;
    const int qA = tid & 3;
    int mA = m0 + rA; if (mA > M - 1) mA = M - 1;
    const int bA = mA >> lgnp;
    const int pA = mA & (np - 1);

    const u16* arow = nullptr;
    const float *erowL = nullptr, *erowR = nullptr;
    if (LEAF) {
        int tl = tokens[bA * 1024 + 2 * pA];
        int tr = tokens[bA * 1024 + 2 * pA + 1];
        erowL = emb + (size_t)tl * 512;
        erowR = emb + (size_t)tr * 512;
    } else {
        arow = Hc + ((size_t)bA * nc + 2 * pA) * 1024;   // 2048 u16, contiguous pair
    }
    // inner A LDS dest: rA*72 + (qA&1)*32 + (qA>>1)*16  (<=2-way banks)
    const int daI = rA * ARW + (qA & 1) * 32 + (qA >> 1) * 16;
    // leaf A LDS dest: k-chunk qA*8, hi at +0, lo at +32
    const int daL = rA * ARW + qA * 8;

    // ---- B fragment bases: per-lane, perfectly coalesced 1KB per wave-instr ----
    const u16* bbH = g_Bhi + ((size_t)(j0 + wc * 16 + il)) * 32 + kq * 8;
    const u16* bbL = g_Blo + ((size_t)(j0 + wc * 16 + il)) * 32 + kq * 8;

    // A staging registers
    uint4  aR0, aR1;
    float4 fR0, fR1;
    // B register sets (static dbuf)
    s16x8 b0h[5], b0l[5], b1h[5], b1l[5];

#define LOADA(t_)                                                              \
    {                                                                          \
        const int t__ = (t_);                                                  \
        if (LEAF) {                                                            \
            const float* asrc = ((t__ < 16) ? erowL : erowR)                   \
                                + ((32 * t__) & 511) + qA * 8;                 \
            fR0 = *(const float4*)asrc;                                        \
            fR1 = *(const float4*)(asrc + 4);                                  \
        } else {                                                               \
            const u16* asrc = arow + t__ * 64 + qA * 16;                       \
            aR0 = *(const uint4*)asrc;                                         \
            aR1 = *(const uint4*)(asrc + 8);                                   \
        }                                                                      \
    }

#define LOADB(BH, BL, t_)                                                      \
    {                                                                          \
        const size_t tb = (size_t)(t_) * 5 * 16384;                            \
        _Pragma("unroll")                                                      \
        for (int g = 0; g < 5; g++) {                                          \
            BH[g] = *(const s16x8*)(bbH + tb + (size_t)g * 16384);             \
            BL[g] = *(const s16x8*)(bbL + tb + (size_t)g * 16384);             \
        }                                                                      \
    }

#define WRITEA(bf)                                                             \
    {                                                                          \
        const int bf__ = (bf);                                                 \
        if (LEAF) {                                                            \
            float v[8] = {fR0.x, fR0.y, fR0.z, fR0.w, fR1.x, fR1.y, fR1.z, fR1.w}; \
            unsigned ph[4], pl[4];                                             \
            _Pragma("unroll")                                                  \
            for (int i = 0; i < 4; i++) {                                      \
                u16 h0 = f2bf(v[2 * i]), h1 = f2bf(v[2 * i + 1]);              \
                u16 l0 = f2bf(v[2 * i] - bf2f(h0));                            \
                u16 l1 = f2bf(v[2 * i + 1] - bf2f(h1));                        \
                ph[i] = pk(h0, h1);  pl[i] = pk(l0, l1);                       \
            }                                                                  \
            *(uint4*)&Ac[bf__][daL]      = make_uint4(ph[0], ph[1], ph[2], ph[3]); \
            *(uint4*)&Ac[bf__][daL + 32] = make_uint4(pl[0], pl[1], pl[2], pl[3]); \
        } else {                                                               \
            *(uint4*)&Ac[bf__][daI]     = aR0;                                 \
            *(uint4*)&Ac[bf__][daI + 8] = aR1;                                 \
        }                                                                      \
    }

#define COMPUTE(BH, BL, BUF)                                                   \
    {                                                                          \
        _Pragma("unroll")                                                      \
        for (int rf = 0; rf < 4; rf++) {                                       \
            const int ao = (wm * 64 + rf * 16 + il) * ARW + kq * 8;            \
            s16x8 ahv = *(const s16x8*)&Ac[BUF][ao];                           \
            s16x8 alv = *(const s16x8*)&Ac[BUF][ao + 32];                      \
            _Pragma("unroll")                                                  \
            for (int g = 0; g < 5; g++) {                                      \
                acc[rf][g] = __builtin_amdgcn_mfma_f32_16x16x32_bf16(ahv, BH[g], acc[rf][g], 0, 0, 0); \
                acc[rf][g] = __builtin_amdgcn_mfma_f32_16x16x32_bf16(ahv, BL[g], acc[rf][g], 0, 0, 0); \
                acc[rf][g] = __builtin_amdgcn_mfma_f32_16x16x32_bf16(alv, BH[g], acc[rf][g], 0, 0, 0); \
            }                                                                  \
        }                                                                      \
    }

    // ================= prologue =================
    LOADA(0);
    LOADB(b0h, b0l, 0);
    WRITEA(0);
    __syncthreads();

#pragma unroll 1
    for (int t = 0; t < NITER; t += 2) {
        // ---- even iter: compute buf0 with b0 ----
        if (t + 1 < NITER) {
            LOADA(t + 1);                 // A issued first (older in vm queue)
            LOADB(b1h, b1l, t + 1);       // B younger -> counted vmcnt keeps them in flight
        }
        COMPUTE(b0h, b0l, 0);
        if (t + 1 < NITER) {
            WRITEA(1);
            __syncthreads();
        }
        // ---- odd iter: compute buf1 with b1 ----
        if (t + 2 < NITER) {
            LOADA(t + 2);
            LOADB(b0h, b0l, t + 2);
        }
        COMPUTE(b1h, b1l, 1);
        if (t + 2 < NITER) {
            WRITEA(0);
            __syncthreads();
        }
    }
#undef LOADA
#undef LOADB
#undef WRITEA
#undef COMPUTE

    // ================= fused LSTM epilogue =================
    const int jglob = j0 + wc * 16 + il;       // 0..511
    const float bi  = b_iou[jglob];
    const float bo_ = b_iou[512 + jglob];
    const float bu  = b_iou[1024 + jglob];
    const float bfl = b_f[jglob];
    const float bfr = b_f[512 + jglob];

#pragma unroll
    for (int rf = 0; rf < 4; rf++) {
#pragma unroll
        for (int r = 0; r < 4; r++) {
            const int m = m0 + wm * 64 + rf * 16 + kq * 4 + r;
            if (m < M) {
                const int b = m >> lgnp;
                const int p = m & (np - 1);
                float i_ = acc[rf][0][r] + bi;
                float o_ = acc[rf][1][r] + bo_;
                float u_ = acc[rf][2][r] + bu;
                float fl = sigm(acc[rf][3][r] + bfl);
                float fr = sigm(acc[rf][4][r] + bfr);
                float cl = 0.0f, cr_ = 0.0f;
                if (!LEAF) {
                    size_t cb_ = ((size_t)b * nc + 2 * p) * 512 + jglob;
                    cl  = Cc[cb_];
                    cr_ = Cc[cb_ + 512];
                }
                float cn = sigm(i_) * tanhf(u_) + fl * cl + fr * cr_;
                float hn = sigm(o_) * tanhf(cn);
                size_t prow = (size_t)b * np + p;
                u16 hh = f2bf(hn);
                u16 hlo = f2bf(hn - bf2f(hh));
                Hp[prow * 1024 + (size_t)(jg * 4 + wc) * 32 + il]      = hh;
                Hp[prow * 1024 + (size_t)(jg * 4 + wc) * 32 + 16 + il] = hlo;
                Cp[prow * 512 + jglob] = cn;
            }
        }
    }
}

// ---------------- out[b][c] = sum_d h_root[b][d] * W_out[d][c] ----------------
__global__ __launch_bounds__(256)
void out_kernel(const u16* __restrict__ Hroot, const float* __restrict__ W_out,
                float* __restrict__ out)
{
    const int b = blockIdx.x;
    const int tid = threadIdx.x;
    float s0 = 0.f, s1 = 0.f;
    for (int d = tid; d < 512; d += 256) {
        const u16* row = Hroot + (size_t)b * 1024 + (d >> 4) * 32 + (d & 15);
        float h = bf2f(row[0]) + bf2f(row[16]);
        s0 = fmaf(h, W_out[d * 2 + 0], s0);
        s1 = fmaf(h, W_out[d * 2 + 1], s1);
    }
#pragma unroll
    for (int off = 32; off > 0; off >>= 1) {
        s0 += __shfl_down(s0, off, 64);
        s1 += __shfl_down(s1, off, 64);
    }
    __shared__ float red[2][4];
    const int wave = tid >> 6;
    if ((tid & 63) == 0) { red[0][wave] = s0; red[1][wave] = s1; }
    __syncthreads();
    if (tid == 0) {
        float t0 = 0.f, t1 = 0.f;
#pragma unroll
        for (int wv = 0; wv < 4; wv++) { t0 += red[0][wv]; t1 += red[1][wv]; }
        out[b * 2 + 0] = t0;
        out[b * 2 + 1] = t1;
    }
}

extern "C" void kernel_launch(void* const* d_in, const int* in_sizes, int n_in,
                              void* d_out, int out_size, void* d_ws, size_t ws_size,
                              hipStream_t stream)
{
    const int*   tokens = (const int*)  d_in[0];
    const float* emb    = (const float*)d_in[1];
    const float* W_iou  = (const float*)d_in[2];
    const float* b_iou  = (const float*)d_in[3];
    const float* W_f    = (const float*)d_in[4];
    const float* b_f    = (const float*)d_in[5];
    const float* W_out  = (const float*)d_in[6];
    float* out = (float*)d_out;

    // ws layout (201.3 MB, proven):
    u16*   H0 = (u16*)d_ws;
    float* C0 = (float*)(H0 + (size_t)512 * 64 * 1024);
    u16*   H1 = (u16*)(C0 + (size_t)512 * 64 * 512);
    float* C1 = (float*)(H1 + (size_t)256 * 64 * 1024);

    wsplit_kernel<<<dim3(32, 40), 256, 0, stream>>>(W_iou, W_f);

    // level 9: leaves -> 512 parents
    level_mfma<true><<<dim3(8, 256), 512, 0, stream>>>(
        nullptr, nullptr, tokens, emb, b_iou, b_f, H0, C0, 512, 9);

    u16* Hc = H0;  float* Cc = C0;
    u16* Hp = H1;  float* Cp = C1;
    for (int L = 8; L >= 0; L--) {
        const int np = 1 << L;
        const int gy = (np * 64 + 127) / 128;
        level_mfma<false><<<dim3(8, gy), 512, 0, stream>>>(
            Hc, Cc, nullptr, nullptr, b_iou, b_f, Hp, Cp, np, L);
        u16* tH = Hc; Hc = Hp; Hp = tH;
        float* tC = Cc; Cc = Cp; Cp = tC;
    }

    out_kernel<<<64, 256, 0, stream>>>(Hc, W_out, out);
}

// Round 6
// 1285.528 us; speedup vs baseline: 1.1830x; 1.1830x over previous
//
#include <hip/hip_runtime.h>
#include <math.h>

typedef unsigned short u16;
typedef short s16x8 __attribute__((ext_vector_type(8)));
typedef float f32x4 __attribute__((ext_vector_type(4)));

#define NITER 32   // K=1024 / BK=32
#define ARW 72     // u16 per A LDS row: [32 hi][32 lo][8 pad] = 144 B

// Pre-split, transposed weights: layout [kb 32][gate 5][j 512][k 32]
__device__ __align__(16) u16 g_Bhi[1024 * 2560];
__device__ __align__(16) u16 g_Blo[1024 * 2560];

__device__ __forceinline__ u16 f2bf(float x) {
    unsigned u = __float_as_uint(x);
    u += 0x7fffu + ((u >> 16) & 1u);       // RNE
    return (u16)(u >> 16);
}
__device__ __forceinline__ float bf2f(u16 h) { return __uint_as_float(((unsigned)h) << 16); }
__device__ __forceinline__ float sigm(float x) { return 1.0f / (1.0f + expf(-x)); }
__device__ __forceinline__ unsigned pk(u16 a, u16 b) { return (unsigned)a | ((unsigned)b << 16); }

// ---------------- weight split+transpose: W[k][col] f32 -> [kb][g][j][k] bf16 hi/lo ----------
__global__ __launch_bounds__(256)
void wsplit_kernel(const float* __restrict__ Wiou, const float* __restrict__ Wf)
{
    __shared__ float tile[32][65];
    const int kb = blockIdx.x;           // 0..31
    const int cb = blockIdx.y;           // 0..39
    const int t  = threadIdx.x;
    const int c0 = cb * 64;

    {   // load 32k x 64c, coalesced on cols
        const int kk  = t >> 3;          // 0..31
        const int cu0 = (t & 7) * 8;     // 0..56
        const int k   = kb * 32 + kk;
#pragma unroll
        for (int u = 0; u < 8; u++) {
            int c = c0 + cu0 + u;
            float v = (c < 1536) ? Wiou[(size_t)k * 1536 + c]
                                 : Wf[(size_t)k * 1024 + (c - 1536)];
            tile[kk][cu0 + u] = v;
        }
    }
    __syncthreads();
    {   // write transposed, split, coalesced on dest
        const int jl = t >> 2;           // 0..63
        const int kc = (t & 3) * 8;      // 0,8,16,24
        const int g  = c0 >> 9;
        const int j  = (c0 & 511) + jl;
        size_t dst = (((size_t)kb * 5 + g) * 512 + j) * 32 + kc;
        unsigned ph[4], pl[4];
#pragma unroll
        for (int u = 0; u < 4; u++) {
            float v0 = tile[kc + 2 * u][jl];
            float v1 = tile[kc + 2 * u + 1][jl];
            u16 h0 = f2bf(v0), h1 = f2bf(v1);
            u16 l0 = f2bf(v0 - bf2f(h0)), l1 = f2bf(v1 - bf2f(h1));
            ph[u] = pk(h0, h1);
            pl[u] = pk(l0, l1);
        }
        *(uint4*)(g_Bhi + dst) = make_uint4(ph[0], ph[1], ph[2], ph[3]);
        *(uint4*)(g_Blo + dst) = make_uint4(pl[0], pl[1], pl[2], pl[3]);
    }
}

// ---------------- one tree level: split-bf16 MFMA GEMM + fused LSTM epilogue ----------------
// H global layout: per row: 1024 u16 = 32 chunks x {16 hi, 16 lo}. A-row = left||right contiguous.
// 256-thread blocks (4 waves, 1/SIMD) so 2 independent blocks co-reside per CU and their
// desynced barriers overlap staging with MFMA (m97/m114 mechanism).
// A: LDS-staged (shared by the 4 wc-waves), 144B combined rows, double-buffered (18.4 KB).
// B: global -> registers (coalesced 1KB/wave-instr, L2-resident, XCD-pinned), dual reg sets.
template<bool LEAF>
__global__ __launch_bounds__(256, 2)
void level_mfma(const u16* __restrict__ Hc, const float* __restrict__ Cc,
                const int* __restrict__ tokens, const float* __restrict__ emb,
                const float* __restrict__ b_iou, const float* __restrict__ b_f,
                u16* __restrict__ Hp, float* __restrict__ Cp,
                int np, int lgnp)
{
    __shared__ __align__(16) u16 Ac[2][64 * ARW];   // 2 x 9.2 KB

    const int tid = threadIdx.x;
    const int jg  = blockIdx.x;          // 0..7 -> XCD pinning via %8
    const int m0  = blockIdx.y * 64;
    const int j0  = jg * 64;
    const int nc  = np * 2;
    const int M   = np * 64;

    // wave compute roles: 4 waves = 4 col groups, all 64 rows each
    const int w    = tid >> 6;
    const int lane = tid & 63;
    const int il   = lane & 15;
    const int kq   = lane >> 4;
    const int wc   = w;                  // j sub-range wc*16 .. +15

    f32x4 acc[4][5];                     // [rowfrag][gate]
#pragma unroll
    for (int rf = 0; rf < 4; rf++)
#pragma unroll
        for (int g = 0; g < 5; g++) acc[rf][g] = (f32x4)0.0f;

    // ---- A staging role: row rA (0..63), quarter qA (0..3) ----
    const int rA = tid >> 2;
    const int qA = tid & 3;
    int mA = m0 + rA; if (mA > M - 1) mA = M - 1;
    const int bA = mA >> lgnp;
    const int pA = mA & (np - 1);

    const u16* arow = nullptr;
    const float *erowL = nullptr, *erowR = nullptr;
    if (LEAF) {
        int tl = tokens[bA * 1024 + 2 * pA];
        int tr = tokens[bA * 1024 + 2 * pA + 1];
        erowL = emb + (size_t)tl * 512;
        erowR = emb + (size_t)tr * 512;
    } else {
        arow = Hc + ((size_t)bA * nc + 2 * pA) * 1024;   // 2048 u16, contiguous pair
    }
    // inner A LDS dest: rA*72 + (qA&1)*32 + (qA>>1)*16  (<=2-way banks)
    const int daI = rA * ARW + (qA & 1) * 32 + (qA >> 1) * 16;
    // leaf A LDS dest: k-chunk qA*8, hi at +0, lo at +32
    const int daL = rA * ARW + qA * 8;

    // ---- B fragment bases: per-lane, 1KB contiguous per wave-instr ----
    const u16* bbH = g_Bhi + ((size_t)(j0 + wc * 16 + il)) * 32 + kq * 8;
    const u16* bbL = g_Blo + ((size_t)(j0 + wc * 16 + il)) * 32 + kq * 8;

    // A staging registers
    uint4  aR0, aR1;
    float4 fR0, fR1;
    // B register sets (static dbuf)
    s16x8 b0h[5], b0l[5], b1h[5], b1l[5];

#define LOADA(t_)                                                              \
    {                                                                          \
        const int t__ = (t_);                                                  \
        if (LEAF) {                                                            \
            const float* asrc = ((t__ < 16) ? erowL : erowR)                   \
                                + ((32 * t__) & 511) + qA * 8;                 \
            fR0 = *(const float4*)asrc;                                        \
            fR1 = *(const float4*)(asrc + 4);                                  \
        } else {                                                               \
            const u16* asrc = arow + t__ * 64 + qA * 16;                       \
            aR0 = *(const uint4*)asrc;                                         \
            aR1 = *(const uint4*)(asrc + 8);                                   \
        }                                                                      \
    }

#define LOADB(BH, BL, t_)                                                      \
    {                                                                          \
        const size_t tb = (size_t)(t_) * 5 * 16384;                            \
        _Pragma("unroll")                                                      \
        for (int g = 0; g < 5; g++) {                                          \
            BH[g] = *(const s16x8*)(bbH + tb + (size_t)g * 16384);             \
            BL[g] = *(const s16x8*)(bbL + tb + (size_t)g * 16384);             \
        }                                                                      \
    }

#define WRITEA(bf)                                                             \
    {                                                                          \
        const int bf__ = (bf);                                                 \
        if (LEAF) {                                                            \
            float v[8] = {fR0.x, fR0.y, fR0.z, fR0.w, fR1.x, fR1.y, fR1.z, fR1.w}; \
            unsigned ph[4], pl[4];                                             \
            _Pragma("unroll")                                                  \
            for (int i = 0; i < 4; i++) {                                      \
                u16 h0 = f2bf(v[2 * i]), h1 = f2bf(v[2 * i + 1]);              \
                u16 l0 = f2bf(v[2 * i] - bf2f(h0));                            \
                u16 l1 = f2bf(v[2 * i + 1] - bf2f(h1));                        \
                ph[i] = pk(h0, h1);  pl[i] = pk(l0, l1);                       \
            }                                                                  \
            *(uint4*)&Ac[bf__][daL]      = make_uint4(ph[0], ph[1], ph[2], ph[3]); \
            *(uint4*)&Ac[bf__][daL + 32] = make_uint4(pl[0], pl[1], pl[2], pl[3]); \
        } else {                                                               \
            *(uint4*)&Ac[bf__][daI]     = aR0;                                 \
            *(uint4*)&Ac[bf__][daI + 8] = aR1;                                 \
        }                                                                      \
    }

#define COMPUTE(BH, BL, BUF)                                                   \
    {                                                                          \
        _Pragma("unroll")                                                      \
        for (int rf = 0; rf < 4; rf++) {                                       \
            const int ao = (rf * 16 + il) * ARW + kq * 8;                      \
            s16x8 ahv = *(const s16x8*)&Ac[BUF][ao];                           \
            s16x8 alv = *(const s16x8*)&Ac[BUF][ao + 32];                      \
            _Pragma("unroll")                                                  \
            for (int g = 0; g < 5; g++) {                                      \
                acc[rf][g] = __builtin_amdgcn_mfma_f32_16x16x32_bf16(ahv, BH[g], acc[rf][g], 0, 0, 0); \
                acc[rf][g] = __builtin_amdgcn_mfma_f32_16x16x32_bf16(ahv, BL[g], acc[rf][g], 0, 0, 0); \
                acc[rf][g] = __builtin_amdgcn_mfma_f32_16x16x32_bf16(alv, BH[g], acc[rf][g], 0, 0, 0); \
            }                                                                  \
        }                                                                      \
    }

    // ================= prologue =================
    LOADA(0);
    LOADB(b0h, b0l, 0);
    WRITEA(0);
    __syncthreads();

#pragma unroll 1
    for (int t = 0; t < NITER; t += 2) {
        // ---- even iter: compute buf0 with b0 ----
        if (t + 1 < NITER) {
            LOADA(t + 1);                 // A issued first (older in vm queue)
            LOADB(b1h, b1l, t + 1);       // B younger -> counted vmcnt keeps them in flight
        }
        COMPUTE(b0h, b0l, 0);
        if (t + 1 < NITER) {
            WRITEA(1);
            __syncthreads();
        }
        // ---- odd iter: compute buf1 with b1 ----
        if (t + 2 < NITER) {
            LOADA(t + 2);
            LOADB(b0h, b0l, t + 2);
        }
        COMPUTE(b1h, b1l, 1);
        if (t + 2 < NITER) {
            WRITEA(0);
            __syncthreads();
        }
    }
#undef LOADA
#undef LOADB
#undef WRITEA
#undef COMPUTE

    // ================= fused LSTM epilogue =================
    const int jglob = j0 + wc * 16 + il;       // 0..511
    const float bi  = b_iou[jglob];
    const float bo_ = b_iou[512 + jglob];
    const float bu  = b_iou[1024 + jglob];
    const float bfl = b_f[jglob];
    const float bfr = b_f[512 + jglob];

#pragma unroll
    for (int rf = 0; rf < 4; rf++) {
#pragma unroll
        for (int r = 0; r < 4; r++) {
            const int m = m0 + rf * 16 + kq * 4 + r;
            if (m < M) {
                const int b = m >> lgnp;
                const int p = m & (np - 1);
                float i_ = acc[rf][0][r] + bi;
                float o_ = acc[rf][1][r] + bo_;
                float u_ = acc[rf][2][r] + bu;
                float fl = sigm(acc[rf][3][r] + bfl);
                float fr = sigm(acc[rf][4][r] + bfr);
                float cl = 0.0f, cr_ = 0.0f;
                if (!LEAF) {
                    size_t cb_ = ((size_t)b * nc + 2 * p) * 512 + jglob;
                    cl  = Cc[cb_];
                    cr_ = Cc[cb_ + 512];
                }
                float cn = sigm(i_) * tanhf(u_) + fl * cl + fr * cr_;
                float hn = sigm(o_) * tanhf(cn);
                size_t prow = (size_t)b * np + p;
                u16 hh = f2bf(hn);
                u16 hlo = f2bf(hn - bf2f(hh));
                Hp[prow * 1024 + (size_t)(jg * 4 + wc) * 32 + il]      = hh;
                Hp[prow * 1024 + (size_t)(jg * 4 + wc) * 32 + 16 + il] = hlo;
                Cp[prow * 512 + jglob] = cn;
            }
        }
    }
}

// ---------------- out[b][c] = sum_d h_root[b][d] * W_out[d][c] ----------------
__global__ __launch_bounds__(256)
void out_kernel(const u16* __restrict__ Hroot, const float* __restrict__ W_out,
                float* __restrict__ out)
{
    const int b = blockIdx.x;
    const int tid = threadIdx.x;
    float s0 = 0.f, s1 = 0.f;
    for (int d = tid; d < 512; d += 256) {
        const u16* row = Hroot + (size_t)b * 1024 + (d >> 4) * 32 + (d & 15);
        float h = bf2f(row[0]) + bf2f(row[16]);
        s0 = fmaf(h, W_out[d * 2 + 0], s0);
        s1 = fmaf(h, W_out[d * 2 + 1], s1);
    }
#pragma unroll
    for (int off = 32; off > 0; off >>= 1) {
        s0 += __shfl_down(s0, off, 64);
        s1 += __shfl_down(s1, off, 64);
    }
    __shared__ float red[2][4];
    const int wave = tid >> 6;
    if ((tid & 63) == 0) { red[0][wave] = s0; red[1][wave] = s1; }
    __syncthreads();
    if (tid == 0) {
        float t0 = 0.f, t1 = 0.f;
#pragma unroll
        for (int wv = 0; wv < 4; wv++) { t0 += red[0][wv]; t1 += red[1][wv]; }
        out[b * 2 + 0] = t0;
        out[b * 2 + 1] = t1;
    }
}

extern "C" void kernel_launch(void* const* d_in, const int* in_sizes, int n_in,
                              void* d_out, int out_size, void* d_ws, size_t ws_size,
                              hipStream_t stream)
{
    const int*   tokens = (const int*)  d_in[0];
    const float* emb    = (const float*)d_in[1];
    const float* W_iou  = (const float*)d_in[2];
    const float* b_iou  = (const float*)d_in[3];
    const float* W_f    = (const float*)d_in[4];
    const float* b_f    = (const float*)d_in[5];
    const float* W_out  = (const float*)d_in[6];
    float* out = (float*)d_out;

    // ws layout (201.3 MB, proven):
    u16*   H0 = (u16*)d_ws;
    float* C0 = (float*)(H0 + (size_t)512 * 64 * 1024);
    u16*   H1 = (u16*)(C0 + (size_t)512 * 64 * 512);
    float* C1 = (float*)(H1 + (size_t)256 * 64 * 1024);

    wsplit_kernel<<<dim3(32, 40), 256, 0, stream>>>(W_iou, W_f);

    // level 9: leaves -> 512 parents
    level_mfma<true><<<dim3(8, 512), 256, 0, stream>>>(
        nullptr, nullptr, tokens, emb, b_iou, b_f, H0, C0, 512, 9);

    u16* Hc = H0;  float* Cc = C0;
    u16* Hp = H1;  float* Cp = C1;
    for (int L = 8; L >= 0; L--) {
        const int np = 1 << L;
        level_mfma<false><<<dim3(8, np), 256, 0, stream>>>(
            Hc, Cc, nullptr, nullptr, b_iou, b_f, Hp, Cp, np, L);
        u16* tH = Hc; Hc = Hp; Hp = tH;
        float* tC = Cc; Cc = Cp; Cp = tC;
    }

    out_kernel<<<64, 256, 0, stream>>>(Hc, W_out, out);
}